// Round 7
// baseline (57.893 us; speedup 1.0000x reference)
//
#include <hip/hip_runtime.h>

#define NT 64
#define TOK 64

#define GL16(gp, lp) __builtin_amdgcn_global_load_lds( \
    (const __attribute__((address_space(1))) void*)(gp), \
    (__attribute__((address_space(3))) void*)(lp), 16, 0, 0)
#define GL4(gp, lp) __builtin_amdgcn_global_load_lds( \
    (const __attribute__((address_space(1))) void*)(gp), \
    (__attribute__((address_space(3))) void*)(lp), 4, 0, 0)
#define WAITVM(N) do { \
    asm volatile("s_waitcnt vmcnt(" #N ")" ::: "memory"); \
    __builtin_amdgcn_sched_barrier(0); \
} while (0)
// Same-wave DS drain + scheduling fence (rule #18) before overwriting a slot we just read.
#define WAITLG() do { \
    asm volatile("s_waitcnt lgkmcnt(0)" ::: "memory"); \
    __builtin_amdgcn_sched_barrier(0); \
} while (0)

#if defined(__has_builtin)
# if __has_builtin(__builtin_amdgcn_exp2f)
#  define EXP2F(x) __builtin_amdgcn_exp2f(x)
# else
#  define EXP2F(x) exp2f(x)
# endif
#else
# define EXP2F(x) exp2f(x)
#endif

// 64 tokens x 45 floats = 720 float4 -> LDS, 12 GL16 per wave (11 full + 16-lane partial).
__device__ __forceinline__ void stage45(const float* __restrict__ g, float* lds, int lane) {
    const float4* g4 = (const float4*)g;
    #pragma unroll
    for (int it = 0; it < 11; ++it)
        GL16(g4 + it * 64 + lane, lds + it * 256);
    if (lane < 16) GL16(g4 + 704 + lane, lds + 2816);
}

// One dist row r for this wave's 64 tokens = 960 floats, 15 GL4 (lane-linear gather:
// consecutive lanes read consecutive floats -> few cache lines per instruction).
__device__ __forceinline__ void stage_row(const float* __restrict__ dr, float* slot,
                                          int off0, int j0) {
    int off = off0, j = j0;
    #pragma unroll
    for (int it = 0; it < 15; ++it) {
        GL4(dr + off, slot + it * 64);
        j += 4;
        bool w = (j >= 15);
        j -= w ? 15 : 0;
        off += w ? 1114 : 904;      // wrap: 5*225-11 ; no-wrap: 4*225+4
    }
}

// dst[h][n] = (|.|) sum_d row[d*15+n]*w[h*3+d] + bb[h]  (stride-45/lane: conflict-free)
template <bool ABS>
__device__ __forceinline__ void projr(const float* row, const float w[9], const float bb[3],
                                      float dst[3][15]) {
    #pragma unroll
    for (int n = 0; n < 15; ++n) {
        float x0 = row[n], x1 = row[15 + n], x2 = row[30 + n];
        #pragma unroll
        for (int h = 0; h < 3; ++h) {
            float y = fmaf(x2, w[h*3+2], fmaf(x1, w[h*3+1], fmaf(x0, w[h*3+0], bb[h])));
            dst[h][n] = ABS ? fabsf(y) : y;
        }
    }
}

// Slot for dist row r: ring-5 over {D0, D1, B0, B1, B2} (B* = thirds of buf, free post-projv).
#define SLOTP(r) ((r) % 5 == 0 ? dring : (r) % 5 == 1 ? dring + 960 : buf + ((r) % 5 - 2) * 960)

// Phase p: counted wait for row p, consume its slot, issue row p+5 into the SAME slot.
// WN guarantees row p retired: rows p+1.. possibly outstanding (15 each).
#define PHASE(p, WN) do { \
    WAITVM(WN); \
    { const float* sl = SLOTP(p) + lane * 15; \
      _Pragma("unroll") \
      for (int jj = 0; jj < 15; ++jj) { \
        float dd = sl[jj]; \
        concat[(p)*3 + 0] = fmaf(dd, vv[0][jj], concat[(p)*3 + 0]); \
        concat[(p)*3 + 1] = fmaf(dd, vv[1][jj], concat[(p)*3 + 1]); \
        concat[(p)*3 + 2] = fmaf(dd, vv[2][jj], concat[(p)*3 + 2]); \
      } } \
    if ((p) <= 9) { WAITLG(); stage_row(dbase + ((p)+5)*15, SLOTP(p), off0, j0); } \
} while (0)

__global__ __launch_bounds__(NT, 2) void mha_spatial_kernel(
    const float* __restrict__ q, const float* __restrict__ k, const float* __restrict__ v,
    const float* __restrict__ dist,
    const float* __restrict__ Wq, const float* __restrict__ bq,
    const float* __restrict__ Wk, const float* __restrict__ bk,
    const float* __restrict__ Wv, const float* __restrict__ bv,
    const float* __restrict__ Wo, const float* __restrict__ bo,
    float* __restrict__ out)
{
    __shared__ __align__(16) float buf[2880];     // 11.25 KB: qkv serial -> dist slots B0-2 -> out
    __shared__ __align__(16) float dring[1920];   // 7.5 KB: dist slots D0, D1
    const int lane = threadIdx.x;                 // one wave per block
    const int base = blockIdx.x * TOK;

    // Tiny projection weights via uniform (scalar) loads. Fold log2(e) into Wq/bq so the
    // softmax uses exp2 directly (|.| commutes with the positive scale).
    const float LOG2E = 1.4426950408889634f;
    float wq[9], wk[9], wv[9], bqv[3], bkv[3], bvv[3];
    #pragma unroll
    for (int i = 0; i < 9; ++i) { wq[i] = Wq[i] * LOG2E; wk[i] = Wk[i]; wv[i] = Wv[i]; }
    #pragma unroll
    for (int i = 0; i < 3; ++i) { bqv[i] = bq[i] * LOG2E; bkv[i] = bk[i]; bvv[i] = bv[i]; }

    float a[3][15], b[3][15], vv[3][15];

    stage45(q + (size_t)base * 45, buf, lane);        // 12 issues
    WAITVM(0);                                        // q landed
    projr<true>(buf + lane * 45, wq, bqv, a);
    WAITLG();
    stage45(k + (size_t)base * 45, buf, lane);        // 12 issues
    WAITVM(0);                                        // k landed
    projr<true>(buf + lane * 45, wk, bkv, b);
    WAITLG();

    const float* dbase = dist + (size_t)base * 225;
    const int tok0 = lane / 15, j0 = lane - tok0 * 15;
    const int off0 = tok0 * 225 + j0;

    stage45(v + (size_t)base * 45, buf, lane);        // 12 issues   [out 12]
    stage_row(dbase +  0, dring,       off0, j0);     // row0 -> D0  [out 27]
    stage_row(dbase + 15, dring + 960, off0, j0);     // row1 -> D1  [out 42]
    WAITVM(30);                                       // v (oldest 12) landed; rows fly
    projr<false>(buf + lane * 45, wv, bvv, vv);
    WAITLG();                                         // buf free
    stage_row(dbase + 30, buf,        off0, j0);      // row2 -> B0  [out <= 75]
    stage_row(dbase + 45, buf +  960, off0, j0);      // row3 -> B1
    stage_row(dbase + 60, buf + 1920, off0, j0);      // row4 -> B2

    // ---- softmax + PV in registers (5 dist rows in flight underneath) ----
    float concat[45];                         // concat[n*3+h]
    #pragma unroll
    for (int h = 0; h < 3; ++h) {
        float amax = a[h][0], bmax = b[h][0];
        #pragma unroll
        for (int n = 1; n < 15; ++n) { amax = fmaxf(amax, a[h][n]); bmax = fmaxf(bmax, b[h][n]); }
        const float mm2 = amax * bmax;        // max of (a.b) in log2 domain
        float zp[4] = {0.f, 0.f, 0.f, 0.f};   // 4-way partial sums: break the Z chain
        float pv[15];
        #pragma unroll
        for (int i = 0; i < 15; ++i) pv[i] = 0.f;
        #pragma unroll
        for (int i = 0; i < 15; ++i)
            #pragma unroll
            for (int j = 0; j < 15; ++j) {
                float t = EXP2F(fmaf(a[h][i], b[h][j], -mm2));
                zp[j & 3] += t;
                pv[i] = fmaf(t, vv[h][j], pv[i]);
            }
        const float rz = 1.f / ((zp[0] + zp[1]) + (zp[2] + zp[3]));
        #pragma unroll
        for (int i = 0; i < 15; ++i) concat[i*3 + h] = pv[i] * rz;
    }
    #pragma unroll
    for (int h = 0; h < 3; ++h)
        #pragma unroll
        for (int j = 0; j < 15; ++j) vv[h][j] *= 2.f;   // fold 2*distances into v

    // ---- 15 dist rows, ring-5, prefetch distance 5, counted vmcnt (never mid-drain) ----
    PHASE( 0, 60); PHASE( 1, 60); PHASE( 2, 60); PHASE( 3, 60);
    PHASE( 4, 60); PHASE( 5, 60); PHASE( 6, 60); PHASE( 7, 60);
    PHASE( 8, 60); PHASE( 9, 60); PHASE(10, 60); PHASE(11, 45);
    PHASE(12, 30); PHASE(13, 15); PHASE(14, 0);
    WAITLG();                                 // phase-14 ds_reads drained

    // ---- output projection: Wo/bo via uniform scalar loads ----
    #pragma unroll 3
    for (int o = 0; o < 45; ++o) {
        float acc = bo[o];
        const float* wr = Wo + o * 45;        // uniform address -> s_load
        #pragma unroll
        for (int cc = 0; cc < 45; ++cc) acc = fmaf(concat[cc], wr[cc], acc);
        buf[lane * 45 + o] = acc;
    }
    WAITLG();                                 // same-wave ds_writes drained
    {
        float4* o4 = (float4*)(out + (size_t)base * 45);
        const float4* s4 = (const float4*)buf;
        #pragma unroll
        for (int it = 0; it < 11; ++it) o4[it * 64 + lane] = s4[it * 64 + lane];
        if (lane < 16) o4[704 + lane] = s4[704 + lane];
    }
}

extern "C" void kernel_launch(void* const* d_in, const int* in_sizes, int n_in,
                              void* d_out, int out_size, void* d_ws, size_t ws_size,
                              hipStream_t stream) {
    const float* q  = (const float*)d_in[0];
    const float* k  = (const float*)d_in[1];
    const float* v  = (const float*)d_in[2];
    const float* ds = (const float*)d_in[3];
    const float* Wq = (const float*)d_in[5];
    const float* bq = (const float*)d_in[6];
    const float* Wk = (const float*)d_in[7];
    const float* bk = (const float*)d_in[8];
    const float* Wv = (const float*)d_in[9];
    const float* bv = (const float*)d_in[10];
    const float* Wo = (const float*)d_in[11];
    const float* bo = (const float*)d_in[12];
    float* out = (float*)d_out;

    // att_val = zeros(4096) at the tail of d_out
    hipMemsetAsync(out + (size_t)32 * 4096 * 45, 0, 4096 * sizeof(float), stream);

    mha_spatial_kernel<<<dim3((32 * 4096) / TOK), dim3(NT), 0, stream>>>(
        q, k, v, ds, Wq, bq, Wk, bk, Wv, bv, Wo, bo, out);
}